// Round 17
// baseline (789.955 us; speedup 1.0000x reference)
//
#include <hip/hip_runtime.h>
#include <hip/hip_bf16.h>

// ---------------------------------------------------------------------------
// PointNet++ (3x set-abstraction + FC head) on MI355X, f32 end-to-end.
// Discrete selections (FPS argmax, ball-query membership) use __fmul_rn /
// __fadd_rn so the f32 arithmetic is bit-identical to numpy's
// ((dx*dx)+(dy*dy))+(dz*dz) evaluation (no FMA contraction).
//
// R17: cascade the twice-proven chain-split overlap (R14: sa hides for free
// under a co-launched fps chain) down the whole pipeline. fps2 and fps3 are
// split into state-carried halves (bit-exact), each half fused with the SA
// chunk whose inputs are already complete:
//   fps2a || sa1(384..511), fps2b || sa2(0..127),
//   fps3a || sa2(128..255), fps3b || sa3(0..63, COUT-split),
//   then sa3(64..127) standalone.
// sa2's R16 COUT split is REVERTED (it ate sa3's savings: duplicate query +
// staging with no latency problem to fix); sa3 keeps its proven split.
// fps1 remains frozen (4 quarters + sa1-chunk overlap, R15-exact).
// ---------------------------------------------------------------------------

#define B_SZ 16

template<int CTRL>
__device__ __forceinline__ float dpp_mv(float v) {
    const int i = __float_as_int(v);
    const int r = __builtin_amdgcn_update_dpp(i, i, CTRL, 0xf, 0xf, false);
    return __int_as_float(r);
}

__device__ __forceinline__ float wave_max_f32(float x) {
    float v = x;
    v = fmaxf(v, dpp_mv<0x111>(v));  // row_shr:1
    v = fmaxf(v, dpp_mv<0x112>(v));  // row_shr:2
    v = fmaxf(v, dpp_mv<0x114>(v));  // row_shr:4
    v = fmaxf(v, dpp_mv<0x118>(v));  // row_shr:8
    v = fmaxf(v, dpp_mv<0x142>(v));  // row_bcast:15
    v = fmaxf(v, dpp_mv<0x143>(v));  // row_bcast:31
    return __uint_as_float(__builtin_amdgcn_readlane(__float_as_uint(v), 63));
}

__device__ __forceinline__ float read_lane_f32(float v, int l) {
    return __uint_as_float(__builtin_amdgcn_readlane(__float_as_uint(v), l));
}

// ---------------- FPS stage 1 body (R12-exact, frozen) ---------------------
template<int N, int NPOINT, int BLOCK, int S0, int S1, bool FIRST>
__device__ __forceinline__ void fps_body(
    const float* __restrict__ xyz,   // (B,N,3)
    float* __restrict__ newxyz,      // (B,NPOINT,3)
    float* __restrict__ dstate,      // (B,N) min-dist carry
    const int b)
{
    constexpr int P  = N / BLOCK;
    constexpr int NW = BLOCK / 64;
    constexpr int O0 = FIRST ? 0 : S0;
    __shared__ float4 part[2][NW];
    __shared__ float  outb[(S1 - O0) * 3];

    const int tid = threadIdx.x;
    const int lane = tid & 63, w = tid >> 6;
    const float* xb = xyz + (size_t)b * N * 3;

    float px[P], py[P], pz[P], dd[P];
    const int base = tid * P;
#pragma unroll
    for (int i = 0; i < P; i++) {
        px[i] = xb[(base + i) * 3 + 0];
        py[i] = xb[(base + i) * 3 + 1];
        pz[i] = xb[(base + i) * 3 + 2];
    }
    float lx, ly, lz;
    if (FIRST) {
#pragma unroll
        for (int i = 0; i < P; i++) dd[i] = 1e10f;
        lx = xb[0]; ly = xb[1]; lz = xb[2];
        if (tid == 0) { outb[0] = lx; outb[1] = ly; outb[2] = lz; }
    } else {
#pragma unroll
        for (int i = 0; i < P; i++) dd[i] = dstate[((size_t)b * P + i) * BLOCK + tid];
        const float* c = newxyz + ((size_t)b * NPOINT + (S0 - 1)) * 3;
        lx = c[0]; ly = c[1]; lz = c[2];
    }

    for (int s = S0; s < S1; s++) {
        float bv = -1.0f, bx = 0.0f, by = 0.0f, bz = 0.0f;
#pragma unroll
        for (int i = 0; i < P; i++) {
            const float dx = px[i] - lx, dy = py[i] - ly, dz = pz[i] - lz;
            const float d2 = __fadd_rn(__fadd_rn(__fmul_rn(dx, dx), __fmul_rn(dy, dy)),
                                       __fmul_rn(dz, dz));
            const float nd = fminf(dd[i], d2);
            dd[i] = nd;
            const bool gt = nd > bv;
            bv = gt ? nd : bv;
            bx = gt ? px[i] : bx;
            by = gt ? py[i] : by;
            bz = gt ? pz[i] : bz;
        }
        // wave max via DPP; lowest tying lane = lowest index range
        const float wmax = wave_max_f32(bv);
        const unsigned long long mset = __ballot(bv == wmax);
        const int li = __ffsll(mset) - 1;
        const int buf = s & 1;
        if (lane == li) part[buf][w] = make_float4(bv, bx, by, bz);
        __syncthreads();
        float cv = -1.0f;
#pragma unroll
        for (int q = 0; q < NW; q++) {
            const float4 pq = part[buf][q];
            const bool gt = pq.x > cv;
            cv = gt ? pq.x : cv;
            lx = gt ? pq.y : lx;
            ly = gt ? pq.z : ly;
            lz = gt ? pq.w : lz;
        }
        if (tid == 0) {
            const int t = (s - O0) * 3;
            outb[t + 0] = lx; outb[t + 1] = ly; outb[t + 2] = lz;
        }
    }
    __syncthreads();
    if (S1 < NPOINT) {
#pragma unroll
        for (int i = 0; i < P; i++)
            dstate[((size_t)b * P + i) * BLOCK + tid] = dd[i];
    }
    float* o = newxyz + ((size_t)b * NPOINT + O0) * 3;
    for (int t = tid; t < (S1 - O0) * 3; t += BLOCK) o[t] = outb[t];
}

template<int N, int NPOINT, int BLOCK, int S0, int S1, bool FIRST>
__global__ __launch_bounds__(BLOCK) void fps_kernel(
    const float* __restrict__ xyz, float* __restrict__ newxyz,
    float* __restrict__ dstate)
{
    fps_body<N, NPOINT, BLOCK, S0, S1, FIRST>(xyz, newxyz, dstate, blockIdx.x);
}

// ---------------- FPS single-wave SEGMENT body (state-carried) -------------
// Steps [S0,S1); FIRST inits dd + emits center 0, else resumes from dstate
// (dstate[b*N + i*64 + lane]) + newxyz[S0-1]. Bit-exact vs unsplit chain.
template<int N, int NPOINT, int S0, int S1, bool FIRST>
__device__ __forceinline__ void fps_wave_seg_body(
    const float* __restrict__ xyz,   // (B,N,3)
    float* __restrict__ newxyz,      // (B,NPOINT,3)
    float* __restrict__ dstate,      // (B,N)
    const int b, const int lane)
{
    constexpr int P = N / 64;
    const float* xb = xyz + (size_t)b * N * 3;

    float px[P], py[P], pz[P], dd[P];
    const int base = lane * P;
#pragma unroll
    for (int i = 0; i < P; i++) {
        px[i] = xb[(base + i) * 3 + 0];
        py[i] = xb[(base + i) * 3 + 1];
        pz[i] = xb[(base + i) * 3 + 2];
    }
    // pin: single-wave chain cannot afford per-step remat VMEM
#pragma unroll
    for (int i = 0; i < P; i++) {
        asm volatile("" : "+v"(px[i]), "+v"(py[i]), "+v"(pz[i]));
    }
    float lx, ly, lz;
    if (FIRST) {
#pragma unroll
        for (int i = 0; i < P; i++) dd[i] = 1e10f;
        lx = xb[0]; ly = xb[1]; lz = xb[2];
        if (lane == 0) {
            float* o = newxyz + (size_t)b * NPOINT * 3;
            o[0] = lx; o[1] = ly; o[2] = lz;
        }
    } else {
#pragma unroll
        for (int i = 0; i < P; i++) dd[i] = dstate[(size_t)b * N + i * 64 + lane];
        const float* c = newxyz + ((size_t)b * NPOINT + (S0 - 1)) * 3;
        lx = c[0]; ly = c[1]; lz = c[2];
    }

    for (int s = S0; s < S1; s++) {
        float bv = -1.0f, bx = 0.0f, by = 0.0f, bz = 0.0f;
#pragma unroll
        for (int i = 0; i < P; i++) {
            const float dx = px[i] - lx, dy = py[i] - ly, dz = pz[i] - lz;
            const float d2 = __fadd_rn(__fadd_rn(__fmul_rn(dx, dx), __fmul_rn(dy, dy)),
                                       __fmul_rn(dz, dz));
            const float nd = fminf(dd[i], d2);
            dd[i] = nd;
            const bool gt = nd > bv;
            bv = gt ? nd : bv;
            bx = gt ? px[i] : bx;
            by = gt ? py[i] : by;
            bz = gt ? pz[i] : bz;
        }
        const float wmax = wave_max_f32(bv);
        const unsigned long long mset = __ballot(bv == wmax);
        const int li = __ffsll(mset) - 1;   // lowest lane = lowest index range
        lx = read_lane_f32(bx, li);
        ly = read_lane_f32(by, li);
        lz = read_lane_f32(bz, li);
        if (lane == 0) {   // no barrier in this loop -> store never drains
            float* o = newxyz + ((size_t)b * NPOINT + s) * 3;
            o[0] = lx; o[1] = ly; o[2] = lz;
        }
    }
    if (S1 < NPOINT) {
#pragma unroll
        for (int i = 0; i < P; i++)
            dstate[(size_t)b * N + i * 64 + lane] = dd[i];
    }
}

// ---------------- fused ball-query + group + MLP + maxpool body ------------
// One wave per (s,b,obase) item; computes channels [obase, obase+R*64).
// gi/h are per-wave LDS slices. AMAX=true folds the global maxpool via uint
// atomicMax (exact: relu outputs >= 0).
template<int N, int S, int CF, int COUT, int R, bool AMAX>
__device__ __forceinline__ void sa_body(
    const float* __restrict__ xyz,   // (B,N,3)
    const float* __restrict__ feat,  // (B,N,CF)
    const float* __restrict__ cent,  // (B,S,3)
    const float* __restrict__ W,     // (CF+3, COUT)
    const float* __restrict__ bias,  // (COUT)
    float* __restrict__ outf,        // (B,S,COUT) or (B,COUT) if AMAX
    const float r2, const int s, const int b, const int lane,
    const int obase, int* __restrict__ gi, float* __restrict__ h)
{
    constexpr int K    = 32;
    constexpr int JT   = 16;
    constexpr int CIN  = CF + 3;
    constexpr int CINP = (CIN + 3) & ~3;   // pad for b128-aligned rows
    constexpr int C4   = CIN & ~3;         // main-loop bound

    const float* xb = xyz  + (size_t)b * N * 3;
    const float* fb = feat + (size_t)b * N * CF;
    const float cx = cent[((size_t)b * S + s) * 3 + 0];
    const float cy = cent[((size_t)b * S + s) * 3 + 1];
    const float cz = cent[((size_t)b * S + s) * 3 + 2];

    // ---- ordered first-K ball query, 4 chunks (256 pts) per round ----
    constexpr int RND = N / 256;
    int total = 0, g0 = 0;
    for (int r0 = 0; r0 < RND; r0++) {
        if (total >= K) break;
        float xs[4], ys[4], zs[4];
#pragma unroll
        for (int c4 = 0; c4 < 4; c4++) {
            const int p = (r0 * 4 + c4) * 64 + lane;
            xs[c4] = xb[p * 3 + 0];
            ys[c4] = xb[p * 3 + 1];
            zs[c4] = xb[p * 3 + 2];
        }
#pragma unroll
        for (int c4 = 0; c4 < 4; c4++) {
            const int p = (r0 * 4 + c4) * 64 + lane;
            const float dx = xs[c4] - cx, dy = ys[c4] - cy, dz = zs[c4] - cz;
            const float d2 = __fadd_rn(__fadd_rn(__fmul_rn(dx, dx), __fmul_rn(dy, dy)),
                                       __fmul_rn(dz, dz));
            const bool v = (d2 <= r2);
            const unsigned long long bal = __ballot(v);
            if (total == 0 && bal != 0ull) g0 = (r0 * 4 + c4) * 64 + (__ffsll(bal) - 1);
            const int pos = total + __popcll(bal & ((1ull << lane) - 1ull));
            if (v && pos < K) gi[pos] = p;
            total += __popcll(bal);
        }
    }
    if (lane == 0 && total < K) {
        for (int q = total; q < K; q++) gi[q] = g0;
    }
    __syncthreads();   // barrier counts are wave-uniform across the block

    float m[R];
#pragma unroll
    for (int r = 0; r < R; r++) m[r] = -1e30f;

    for (int pass = 0; pass < K / JT; pass++) {
        // ---- stage h[jj][c] for this neighbor tile ----
        for (int jj = 0; jj < JT; jj++) {
            const int idx = gi[pass * JT + jj];
            for (int c = lane; c < CIN; c += 64) {
                float val;
                if (c < 3) {
                    const float cc = (c == 0) ? cx : ((c == 1) ? cy : cz);
                    val = xb[idx * 3 + c] - cc;
                } else {
                    val = fb[(size_t)idx * CF + (c - 3)];
                }
                h[jj * CINP + c] = val;
            }
        }
        __syncthreads();

        // ---- MLP: acc[jj][r] over channels, b128 broadcast h reads ----
        float acc[JT][R];
#pragma unroll
        for (int jj = 0; jj < JT; jj++)
#pragma unroll
            for (int r = 0; r < R; r++) acc[jj][r] = 0.0f;

        const float* wp = W + obase + lane;
        int c = 0;
        for (; c < C4; c += 4) {
            float wv[4][R];
#pragma unroll
            for (int q = 0; q < 4; q++)
#pragma unroll
                for (int r = 0; r < R; r++)
                    wv[q][r] = wp[(size_t)(c + q) * COUT + r * 64];
#pragma unroll
            for (int jj = 0; jj < JT; jj++) {
                const float4 hv = *(const float4*)&h[jj * CINP + c];
#pragma unroll
                for (int r = 0; r < R; r++) {
                    acc[jj][r] = fmaf(hv.x, wv[0][r], acc[jj][r]);
                    acc[jj][r] = fmaf(hv.y, wv[1][r], acc[jj][r]);
                    acc[jj][r] = fmaf(hv.z, wv[2][r], acc[jj][r]);
                    acc[jj][r] = fmaf(hv.w, wv[3][r], acc[jj][r]);
                }
            }
        }
        for (; c < CIN; c++) {
            float wv[R];
#pragma unroll
            for (int r = 0; r < R; r++) wv[r] = wp[(size_t)c * COUT + r * 64];
#pragma unroll
            for (int jj = 0; jj < JT; jj++) {
                const float hv = h[jj * CINP + c];
#pragma unroll
                for (int r = 0; r < R; r++)
                    acc[jj][r] = fmaf(hv, wv[r], acc[jj][r]);
            }
        }
#pragma unroll
        for (int jj = 0; jj < JT; jj++)
#pragma unroll
            for (int r = 0; r < R; r++) m[r] = fmaxf(m[r], acc[jj][r]);
        __syncthreads();   // before next pass overwrites h
    }

#pragma unroll
    for (int r = 0; r < R; r++) {
        const int o = obase + r * 64 + lane;
        const float val = fmaxf(bias[o] + m[r], 0.0f);
        if (AMAX) {
            atomicMax((unsigned*)&outf[(size_t)b * COUT + o], __float_as_uint(val));
        } else {
            outf[((size_t)b * S + s) * COUT + o] = val;
        }
    }
}

// ---------------- standalone sa kernel (center range + COUT split) ---------
template<int N, int S, int CF, int COUT, int R, int SOFF, int HALVES, bool AMAX>
__global__ __launch_bounds__(64) void sa_kernel(
    const float* __restrict__ xyz, const float* __restrict__ feat,
    const float* __restrict__ cent, const float* __restrict__ W,
    const float* __restrict__ bias, float* __restrict__ outf, const float r2)
{
    constexpr int CINP = (CF + 3 + 3) & ~3;
    __shared__ int   gi[32];
    __shared__ float h[16 * CINP];
    const int s = SOFF + blockIdx.x / HALVES;
    const int obase = (blockIdx.x % HALVES) * R * 64;
    sa_body<N, S, CF, COUT, R, AMAX>(xyz, feat, cent, W, bias, outf, r2,
                                     s, blockIdx.y, threadIdx.x, obase, gi, h);
}

// ---------------- fused fps1-quarter || sa1-chunk (512-thr blocks) ---------
template<int S0, int S1, int SOFF, int SCNT>
__global__ __launch_bounds__(512) void fused_fps1_sa_kernel(
    const float* __restrict__ fxyz, float* __restrict__ fnew,
    float* __restrict__ fdd,
    const float* __restrict__ xyz, const float* __restrict__ feat,
    const float* __restrict__ cent, const float* __restrict__ W,
    const float* __restrict__ bias, float* __restrict__ outf, const float r2)
{
    constexpr int CINP = 8;   // CF=3 -> CIN=6 -> pad 8
    if (blockIdx.x < B_SZ) {
        __builtin_amdgcn_s_setprio(3);   // protect the serial chain
        fps_body<4096, 512, 512, S0, S1, false>(fxyz, fnew, fdd, blockIdx.x);
    } else {
        __shared__ int   gi_s[8][32];
        __shared__ float h_s[8][16 * CINP];
        const int w = threadIdx.x >> 6, lane = threadIdx.x & 63;
        const int widx = (blockIdx.x - B_SZ) * 8 + w;
        const int b = widx / SCNT, s = SOFF + widx % SCNT;
        sa_body<4096, 512, 3, 64, 1, false>(xyz, feat, cent, W, bias, outf, r2,
                                            s, b, lane, 0, gi_s[w], h_s[w]);
    }
}

// ---------------- fused fps-wave-segment || sa kernel (64-thr blocks) ------
template<int NF, int NPF, int FS0, int FS1, bool FFIRST,
         int N, int S, int CF, int COUT, int R,
         int SOFF, int SCNT, int HALVES, bool AMAX, bool ZERO>
__global__ __launch_bounds__(64) void fused_fpsw_sa_kernel(
    const float* __restrict__ fxyz,  // fps input  (B,NF,3)
    float* __restrict__ fnew,        // fps output (B,NPF,3)
    float* __restrict__ fdst,        // fps dd state (B,NF)
    const float* __restrict__ xyz, const float* __restrict__ feat,
    const float* __restrict__ cent, const float* __restrict__ W,
    const float* __restrict__ bias, float* __restrict__ outf,
    float* __restrict__ fmx, const float r2)
{
    constexpr int CINP = (CF + 3 + 3) & ~3;
    if (blockIdx.x < B_SZ) {
        if (ZERO) {
            ((float4*)fmx)[blockIdx.x * 64 + threadIdx.x] =
                make_float4(0.f, 0.f, 0.f, 0.f);
        }
        __builtin_amdgcn_s_setprio(3);   // protect the serial chain
        fps_wave_seg_body<NF, NPF, FS0, FS1, FFIRST>(fxyz, fnew, fdst,
                                                     blockIdx.x, threadIdx.x);
    } else {
        __shared__ int   gi[32];
        __shared__ float h[16 * CINP];
        const int i = blockIdx.x - B_SZ;
        const int obase = (i % HALVES) * R * 64;
        const int j = i / HALVES;
        sa_body<N, S, CF, COUT, R, AMAX>(xyz, feat, cent, W, bias, outf, r2,
                                         SOFF + j % SCNT, j / SCNT,
                                         threadIdx.x, obase, gi, h);
    }
}

// ---------------- head part 1: fc1 (parallel, 64 blocks) -------------------
__global__ __launch_bounds__(64) void fc1_kernel(
    const float* __restrict__ f,     // (16,256) pooled features
    const float* __restrict__ w,     // (256,256)
    const float* __restrict__ bias,  // (256)
    float* __restrict__ x1h)         // (16,256) pre-BN fc1 output
{
    const int r = blockIdx.x >> 2;
    const int o = (blockIdx.x & 3) * 64 + threadIdx.x;
    const float* fr = f + r * 256;   // wave-uniform reads (scalar loads)
    float acc = bias[o];
    for (int c = 0; c < 256; c += 4) {
        acc = fmaf(fr[c + 0], w[(size_t)(c + 0) * 256 + o], acc);
        acc = fmaf(fr[c + 1], w[(size_t)(c + 1) * 256 + o], acc);
        acc = fmaf(fr[c + 2], w[(size_t)(c + 2) * 256 + o], acc);
        acc = fmaf(fr[c + 3], w[(size_t)(c + 3) * 256 + o], acc);
    }
    x1h[r * 256 + o] = acc;
}

// ---------------- head part 2: bn1+relu, fc2+bn2+relu, fc3 -----------------
__global__ __launch_bounds__(256) void head2_kernel(
    const float* __restrict__ x1h,   // (16,256) fc1 output
    const float* __restrict__ fc2_w, const float* __restrict__ fc2_b,
    const float* __restrict__ fc3_w, const float* __restrict__ fc3_b,
    const float* __restrict__ bn1_g, const float* __restrict__ bn1_b,
    const float* __restrict__ bn2_g, const float* __restrict__ bn2_b,
    float* __restrict__ out)         // (16,12)
{
    __shared__ float x1[16 * 257];
    __shared__ float x2[16 * 129];
    const int tid = threadIdx.x;

    for (int idx = tid; idx < 16 * 256; idx += 256) {
        const int r = idx >> 8, c = idx & 255;
        x1[r * 257 + c] = x1h[idx];
    }
    __syncthreads();
    // bn1 + relu (per output channel, batch of 16)
    {
        const int o = tid;
        float v[16];
#pragma unroll
        for (int r = 0; r < 16; r++) v[r] = x1[r * 257 + o];
        float m = 0.0f;
#pragma unroll
        for (int r = 0; r < 16; r++) m += v[r];
        m *= (1.0f / 16.0f);
        float var = 0.0f;
#pragma unroll
        for (int r = 0; r < 16; r++) { const float d = v[r] - m; var += d * d; }
        var *= (1.0f / 16.0f);
        const float sc = bn1_g[o] / sqrtf(var + 1e-5f);
        const float sh = bn1_b[o];
#pragma unroll
        for (int r = 0; r < 16; r++)
            x1[r * 257 + o] = fmaxf((v[r] - m) * sc + sh, 0.0f);
    }
    __syncthreads();
    // fc2: thread (r,g) -> row r, cols g*8..g*8+7
    {
        const int r = tid >> 4, g = tid & 15;
        float acc[8];
#pragma unroll
        for (int i = 0; i < 8; i++) acc[i] = fc2_b[g * 8 + i];
        const float* wrow = fc2_w + g * 8;
        for (int c = 0; c < 256; c++) {
            const float fv = x1[r * 257 + c];
            const float4* w4 = (const float4*)(wrow + (size_t)c * 128);
#pragma unroll
            for (int q = 0; q < 2; q++) {
                const float4 wv = w4[q];
                acc[q * 4 + 0] = fmaf(fv, wv.x, acc[q * 4 + 0]);
                acc[q * 4 + 1] = fmaf(fv, wv.y, acc[q * 4 + 1]);
                acc[q * 4 + 2] = fmaf(fv, wv.z, acc[q * 4 + 2]);
                acc[q * 4 + 3] = fmaf(fv, wv.w, acc[q * 4 + 3]);
            }
        }
#pragma unroll
        for (int i = 0; i < 8; i++) x2[r * 129 + g * 8 + i] = acc[i];
    }
    __syncthreads();
    // bn2 + relu
    if (tid < 128) {
        const int o = tid;
        float v[16];
#pragma unroll
        for (int r = 0; r < 16; r++) v[r] = x2[r * 129 + o];
        float m = 0.0f;
#pragma unroll
        for (int r = 0; r < 16; r++) m += v[r];
        m *= (1.0f / 16.0f);
        float var = 0.0f;
#pragma unroll
        for (int r = 0; r < 16; r++) { const float d = v[r] - m; var += d * d; }
        var *= (1.0f / 16.0f);
        const float sc = bn2_g[o] / sqrtf(var + 1e-5f);
        const float sh = bn2_b[o];
#pragma unroll
        for (int r = 0; r < 16; r++)
            x2[r * 129 + o] = fmaxf((v[r] - m) * sc + sh, 0.0f);
    }
    __syncthreads();
    // fc3: 16x12 outputs
    if (tid < 192) {
        const int r = tid / 12, j = tid - r * 12;
        float acc = fc3_b[j];
        for (int c = 0; c < 128; c++)
            acc = fmaf(x2[r * 129 + c], fc3_w[c * 12 + j], acc);
        out[r * 12 + j] = acc;
    }
}

// ---------------------------------------------------------------------------
extern "C" void kernel_launch(void* const* d_in, const int* in_sizes, int n_in,
                              void* d_out, int out_size, void* d_ws, size_t ws_size,
                              hipStream_t stream) {
    const float* points = (const float*)d_in[0];
    const float* W1     = (const float*)d_in[1];
    const float* b1     = (const float*)d_in[2];
    const float* W2     = (const float*)d_in[3];
    const float* b2     = (const float*)d_in[4];
    const float* W3     = (const float*)d_in[5];
    const float* b3     = (const float*)d_in[6];
    const float* fc1_w  = (const float*)d_in[7];
    const float* fc1_b  = (const float*)d_in[8];
    const float* fc2_w  = (const float*)d_in[9];
    const float* fc2_b  = (const float*)d_in[10];
    const float* fc3_w  = (const float*)d_in[11];
    const float* fc3_b  = (const float*)d_in[12];
    const float* bn1_g  = (const float*)d_in[13];
    const float* bn1_b  = (const float*)d_in[14];
    const float* bn2_g  = (const float*)d_in[15];
    const float* bn2_b  = (const float*)d_in[16];
    float* out = (float*)d_out;

    float* ws   = (float*)d_ws;
    float* nx1  = ws;                 // 16*512*3   = 24576
    float* f1   = nx1 + 24576;        // 16*512*64  = 524288
    float* nx2  = f1  + 524288;       // 16*256*3   = 12288
    float* f2   = nx2 + 12288;        // 16*256*128 = 524288
    float* nx3  = f2  + 524288;       // 16*128*3   = 6144
    float* fmx  = nx3 + 6144;         // 16*256     = 4096
    float* fdd  = fmx + 4096;         // 16*4096    = 65536 (fps1 dd carry)
    float* fdd2 = fdd + 65536;        // 16*512     = 8192  (fps2 dd carry)
    float* fdd3 = fdd2 + 8192;        // 16*256     = 4096  (fps3 dd carry)
    float* x1h  = fdd3 + 4096;        // 16*256     = 4096  (fc1 output)

    const float r21 = (float)(0.2 * 0.2);
    const float r22 = (float)(0.4 * 0.4);
    const float r23 = (float)(0.8 * 0.8);

    // fps1 q1 (centers 0..127; nothing to overlap - no sa work ready)
    fps_kernel<4096, 512, 512, 1, 128, true><<<B_SZ, 512, 0, stream>>>(
        points, nx1, fdd);
    // fps1 q2 || sa1(0..127)
    fused_fps1_sa_kernel<128, 256, 0, 128><<<B_SZ + 256, 512, 0, stream>>>(
        points, nx1, fdd, points, points, nx1, W1, b1, f1, r21);
    // fps1 q3 || sa1(128..255)
    fused_fps1_sa_kernel<256, 384, 128, 128><<<B_SZ + 256, 512, 0, stream>>>(
        points, nx1, fdd, points, points, nx1, W1, b1, f1, r21);
    // fps1 q4 || sa1(256..383)
    fused_fps1_sa_kernel<384, 512, 256, 128><<<B_SZ + 256, 512, 0, stream>>>(
        points, nx1, fdd, points, points, nx1, W1, b1, f1, r21);
    // fps2a (nx2 centers 0..127) || sa1(384..511); fps blocks zero fmx
    fused_fpsw_sa_kernel<512, 256, 1, 128, true,
                         4096, 512, 3, 64, 1, 384, 128, 1, false, true>
        <<<B_SZ + 128 * B_SZ, 64, 0, stream>>>(
        nx1, nx2, fdd2, points, points, nx1, W1, b1, f1, fmx, r21);
    // fps2b (nx2 centers 128..255) || sa2(0..127)
    fused_fpsw_sa_kernel<512, 256, 128, 256, false,
                         512, 256, 64, 128, 2, 0, 128, 1, false, false>
        <<<B_SZ + 128 * B_SZ, 64, 0, stream>>>(
        nx1, nx2, fdd2, nx1, f1, nx2, W2, b2, f2, fmx, r22);
    // fps3a (nx3 centers 0..63) || sa2(128..255)
    fused_fpsw_sa_kernel<256, 128, 1, 64, true,
                         512, 256, 64, 128, 2, 128, 128, 1, false, false>
        <<<B_SZ + 128 * B_SZ, 64, 0, stream>>>(
        nx2, nx3, fdd3, nx1, f1, nx2, W2, b2, f2, fmx, r22);
    // fps3b (nx3 centers 64..127) || sa3(centers 0..63, COUT split, atomicMax)
    fused_fpsw_sa_kernel<256, 128, 64, 128, false,
                         256, 128, 128, 256, 2, 0, 64, 2, true, false>
        <<<B_SZ + 64 * 2 * B_SZ, 64, 0, stream>>>(
        nx2, nx3, fdd3, nx2, f2, nx3, W3, b3, fmx, fmx, r23);
    // sa3(centers 64..127, COUT split, atomicMax)
    sa_kernel<256, 128, 128, 256, 2, 64, 2, true>
        <<<dim3(64 * 2, B_SZ), 64, 0, stream>>>(
        nx2, f2, nx3, W3, b3, fmx, r23);
    // head: parallel fc1, then bn/fc2/bn/fc3
    fc1_kernel<<<64, 64, 0, stream>>>(fmx, fc1_w, fc1_b, x1h);
    head2_kernel<<<1, 256, 0, stream>>>(x1h, fc2_w, fc2_b, fc3_w, fc3_b,
                                        bn1_g, bn1_b, bn2_g, bn2_b, out);
}

// Round 18
// 707.883 us; speedup vs baseline: 1.1159x; 1.1159x over previous
//
#include <hip/hip_runtime.h>
#include <hip/hip_bf16.h>

// ---------------------------------------------------------------------------
// PointNet++ (3x set-abstraction + FC head) on MI355X, f32 end-to-end.
// Discrete selections (FPS argmax, ball-query membership) use __fmul_rn /
// __fadd_rn so the f32 arithmetic is bit-identical to numpy's
// ((dx*dx)+(dy*dy))+(dz*dz) evaluation (no FMA contraction).
//
// R18: best-measured assembly. Base = R15 (710us: frozen fps1 in 4 quarters
// with sa1 chunks hidden under q2/q3/q4, whole fps2 || sa1(384..511), whole
// fps3 || sa2, standalone sa3, split head) + the one proven R16 win: sa3
// COUT split (R=2, HALVES=2 -> 110us -> <92us measured). R17's fps2/fps3
// cascade REVERTED (+70us: max(fps-seg, sa-chunk) gating with no slack,
// extra launches/state); R16's sa2 split REVERTED (+35us: duplicated query/
// staging for a stage that wasn't latency-bound).
// ---------------------------------------------------------------------------

#define B_SZ 16

template<int CTRL>
__device__ __forceinline__ float dpp_mv(float v) {
    const int i = __float_as_int(v);
    const int r = __builtin_amdgcn_update_dpp(i, i, CTRL, 0xf, 0xf, false);
    return __int_as_float(r);
}

__device__ __forceinline__ float wave_max_f32(float x) {
    float v = x;
    v = fmaxf(v, dpp_mv<0x111>(v));  // row_shr:1
    v = fmaxf(v, dpp_mv<0x112>(v));  // row_shr:2
    v = fmaxf(v, dpp_mv<0x114>(v));  // row_shr:4
    v = fmaxf(v, dpp_mv<0x118>(v));  // row_shr:8
    v = fmaxf(v, dpp_mv<0x142>(v));  // row_bcast:15
    v = fmaxf(v, dpp_mv<0x143>(v));  // row_bcast:31
    return __uint_as_float(__builtin_amdgcn_readlane(__float_as_uint(v), 63));
}

__device__ __forceinline__ float read_lane_f32(float v, int l) {
    return __uint_as_float(__builtin_amdgcn_readlane(__float_as_uint(v), l));
}

// ---------------- FPS stage 1 body (R12-exact, frozen) ---------------------
template<int N, int NPOINT, int BLOCK, int S0, int S1, bool FIRST>
__device__ __forceinline__ void fps_body(
    const float* __restrict__ xyz,   // (B,N,3)
    float* __restrict__ newxyz,      // (B,NPOINT,3)
    float* __restrict__ dstate,      // (B,N) min-dist carry
    const int b)
{
    constexpr int P  = N / BLOCK;
    constexpr int NW = BLOCK / 64;
    constexpr int O0 = FIRST ? 0 : S0;
    __shared__ float4 part[2][NW];
    __shared__ float  outb[(S1 - O0) * 3];

    const int tid = threadIdx.x;
    const int lane = tid & 63, w = tid >> 6;
    const float* xb = xyz + (size_t)b * N * 3;

    float px[P], py[P], pz[P], dd[P];
    const int base = tid * P;
#pragma unroll
    for (int i = 0; i < P; i++) {
        px[i] = xb[(base + i) * 3 + 0];
        py[i] = xb[(base + i) * 3 + 1];
        pz[i] = xb[(base + i) * 3 + 2];
    }
    float lx, ly, lz;
    if (FIRST) {
#pragma unroll
        for (int i = 0; i < P; i++) dd[i] = 1e10f;
        lx = xb[0]; ly = xb[1]; lz = xb[2];
        if (tid == 0) { outb[0] = lx; outb[1] = ly; outb[2] = lz; }
    } else {
#pragma unroll
        for (int i = 0; i < P; i++) dd[i] = dstate[((size_t)b * P + i) * BLOCK + tid];
        const float* c = newxyz + ((size_t)b * NPOINT + (S0 - 1)) * 3;
        lx = c[0]; ly = c[1]; lz = c[2];
    }

    for (int s = S0; s < S1; s++) {
        float bv = -1.0f, bx = 0.0f, by = 0.0f, bz = 0.0f;
#pragma unroll
        for (int i = 0; i < P; i++) {
            const float dx = px[i] - lx, dy = py[i] - ly, dz = pz[i] - lz;
            const float d2 = __fadd_rn(__fadd_rn(__fmul_rn(dx, dx), __fmul_rn(dy, dy)),
                                       __fmul_rn(dz, dz));
            const float nd = fminf(dd[i], d2);
            dd[i] = nd;
            const bool gt = nd > bv;
            bv = gt ? nd : bv;
            bx = gt ? px[i] : bx;
            by = gt ? py[i] : by;
            bz = gt ? pz[i] : bz;
        }
        // wave max via DPP; lowest tying lane = lowest index range
        const float wmax = wave_max_f32(bv);
        const unsigned long long mset = __ballot(bv == wmax);
        const int li = __ffsll(mset) - 1;
        const int buf = s & 1;
        if (lane == li) part[buf][w] = make_float4(bv, bx, by, bz);
        __syncthreads();
        float cv = -1.0f;
#pragma unroll
        for (int q = 0; q < NW; q++) {
            const float4 pq = part[buf][q];
            const bool gt = pq.x > cv;
            cv = gt ? pq.x : cv;
            lx = gt ? pq.y : lx;
            ly = gt ? pq.z : ly;
            lz = gt ? pq.w : lz;
        }
        if (tid == 0) {
            const int t = (s - O0) * 3;
            outb[t + 0] = lx; outb[t + 1] = ly; outb[t + 2] = lz;
        }
    }
    __syncthreads();
    if (S1 < NPOINT) {
#pragma unroll
        for (int i = 0; i < P; i++)
            dstate[((size_t)b * P + i) * BLOCK + tid] = dd[i];
    }
    float* o = newxyz + ((size_t)b * NPOINT + O0) * 3;
    for (int t = tid; t < (S1 - O0) * 3; t += BLOCK) o[t] = outb[t];
}

template<int N, int NPOINT, int BLOCK, int S0, int S1, bool FIRST>
__global__ __launch_bounds__(BLOCK) void fps_kernel(
    const float* __restrict__ xyz, float* __restrict__ newxyz,
    float* __restrict__ dstate)
{
    fps_body<N, NPOINT, BLOCK, S0, S1, FIRST>(xyz, newxyz, dstate, blockIdx.x);
}

// ---------------- FPS (single-wave body): no barriers, no LDS --------------
template<int N, int NPOINT>
__device__ __forceinline__ void fps_wave_body(
    const float* __restrict__ xyz,   // (B,N,3)
    float* __restrict__ newxyz,      // (B,NPOINT,3)
    const int b, const int lane)
{
    constexpr int P = N / 64;
    const float* xb = xyz + (size_t)b * N * 3;

    float px[P], py[P], pz[P], dd[P];
    const int base = lane * P;
#pragma unroll
    for (int i = 0; i < P; i++) {
        px[i] = xb[(base + i) * 3 + 0];
        py[i] = xb[(base + i) * 3 + 1];
        pz[i] = xb[(base + i) * 3 + 2];
        dd[i] = 1e10f;
    }
    // pin: single-wave chain cannot afford per-step remat VMEM
#pragma unroll
    for (int i = 0; i < P; i++) {
        asm volatile("" : "+v"(px[i]), "+v"(py[i]), "+v"(pz[i]));
    }
    float lx = xb[0], ly = xb[1], lz = xb[2];
    if (lane == 0) {
        float* o = newxyz + (size_t)b * NPOINT * 3;
        o[0] = lx; o[1] = ly; o[2] = lz;
    }

    for (int s = 1; s < NPOINT; s++) {
        float bv = -1.0f, bx = 0.0f, by = 0.0f, bz = 0.0f;
#pragma unroll
        for (int i = 0; i < P; i++) {
            const float dx = px[i] - lx, dy = py[i] - ly, dz = pz[i] - lz;
            const float d2 = __fadd_rn(__fadd_rn(__fmul_rn(dx, dx), __fmul_rn(dy, dy)),
                                       __fmul_rn(dz, dz));
            const float nd = fminf(dd[i], d2);
            dd[i] = nd;
            const bool gt = nd > bv;
            bv = gt ? nd : bv;
            bx = gt ? px[i] : bx;
            by = gt ? py[i] : by;
            bz = gt ? pz[i] : bz;
        }
        const float wmax = wave_max_f32(bv);
        const unsigned long long mset = __ballot(bv == wmax);
        const int li = __ffsll(mset) - 1;   // lowest lane = lowest index range
        lx = read_lane_f32(bx, li);
        ly = read_lane_f32(by, li);
        lz = read_lane_f32(bz, li);
        if (lane == 0) {   // no barrier in this loop -> store never drains
            float* o = newxyz + ((size_t)b * NPOINT + s) * 3;
            o[0] = lx; o[1] = ly; o[2] = lz;
        }
    }
}

// ---------------- fused ball-query + group + MLP + maxpool body ------------
// One wave per (s,b,obase) item; computes channels [obase, obase+R*64).
// gi/h are per-wave LDS slices. AMAX=true folds the global maxpool via uint
// atomicMax (exact: relu outputs >= 0).
template<int N, int S, int CF, int COUT, int R, bool AMAX>
__device__ __forceinline__ void sa_body(
    const float* __restrict__ xyz,   // (B,N,3)
    const float* __restrict__ feat,  // (B,N,CF)
    const float* __restrict__ cent,  // (B,S,3)
    const float* __restrict__ W,     // (CF+3, COUT)
    const float* __restrict__ bias,  // (COUT)
    float* __restrict__ outf,        // (B,S,COUT) or (B,COUT) if AMAX
    const float r2, const int s, const int b, const int lane,
    const int obase, int* __restrict__ gi, float* __restrict__ h)
{
    constexpr int K    = 32;
    constexpr int JT   = 16;
    constexpr int CIN  = CF + 3;
    constexpr int CINP = (CIN + 3) & ~3;   // pad for b128-aligned rows
    constexpr int C4   = CIN & ~3;         // main-loop bound

    const float* xb = xyz  + (size_t)b * N * 3;
    const float* fb = feat + (size_t)b * N * CF;
    const float cx = cent[((size_t)b * S + s) * 3 + 0];
    const float cy = cent[((size_t)b * S + s) * 3 + 1];
    const float cz = cent[((size_t)b * S + s) * 3 + 2];

    // ---- ordered first-K ball query, 4 chunks (256 pts) per round ----
    constexpr int RND = N / 256;
    int total = 0, g0 = 0;
    for (int r0 = 0; r0 < RND; r0++) {
        if (total >= K) break;
        float xs[4], ys[4], zs[4];
#pragma unroll
        for (int c4 = 0; c4 < 4; c4++) {
            const int p = (r0 * 4 + c4) * 64 + lane;
            xs[c4] = xb[p * 3 + 0];
            ys[c4] = xb[p * 3 + 1];
            zs[c4] = xb[p * 3 + 2];
        }
#pragma unroll
        for (int c4 = 0; c4 < 4; c4++) {
            const int p = (r0 * 4 + c4) * 64 + lane;
            const float dx = xs[c4] - cx, dy = ys[c4] - cy, dz = zs[c4] - cz;
            const float d2 = __fadd_rn(__fadd_rn(__fmul_rn(dx, dx), __fmul_rn(dy, dy)),
                                       __fmul_rn(dz, dz));
            const bool v = (d2 <= r2);
            const unsigned long long bal = __ballot(v);
            if (total == 0 && bal != 0ull) g0 = (r0 * 4 + c4) * 64 + (__ffsll(bal) - 1);
            const int pos = total + __popcll(bal & ((1ull << lane) - 1ull));
            if (v && pos < K) gi[pos] = p;
            total += __popcll(bal);
        }
    }
    if (lane == 0 && total < K) {
        for (int q = total; q < K; q++) gi[q] = g0;
    }
    __syncthreads();   // barrier counts are wave-uniform across the block

    float m[R];
#pragma unroll
    for (int r = 0; r < R; r++) m[r] = -1e30f;

    for (int pass = 0; pass < K / JT; pass++) {
        // ---- stage h[jj][c] for this neighbor tile ----
        for (int jj = 0; jj < JT; jj++) {
            const int idx = gi[pass * JT + jj];
            for (int c = lane; c < CIN; c += 64) {
                float val;
                if (c < 3) {
                    const float cc = (c == 0) ? cx : ((c == 1) ? cy : cz);
                    val = xb[idx * 3 + c] - cc;
                } else {
                    val = fb[(size_t)idx * CF + (c - 3)];
                }
                h[jj * CINP + c] = val;
            }
        }
        __syncthreads();

        // ---- MLP: acc[jj][r] over channels, b128 broadcast h reads ----
        float acc[JT][R];
#pragma unroll
        for (int jj = 0; jj < JT; jj++)
#pragma unroll
            for (int r = 0; r < R; r++) acc[jj][r] = 0.0f;

        const float* wp = W + obase + lane;
        int c = 0;
        for (; c < C4; c += 4) {
            float wv[4][R];
#pragma unroll
            for (int q = 0; q < 4; q++)
#pragma unroll
                for (int r = 0; r < R; r++)
                    wv[q][r] = wp[(size_t)(c + q) * COUT + r * 64];
#pragma unroll
            for (int jj = 0; jj < JT; jj++) {
                const float4 hv = *(const float4*)&h[jj * CINP + c];
#pragma unroll
                for (int r = 0; r < R; r++) {
                    acc[jj][r] = fmaf(hv.x, wv[0][r], acc[jj][r]);
                    acc[jj][r] = fmaf(hv.y, wv[1][r], acc[jj][r]);
                    acc[jj][r] = fmaf(hv.z, wv[2][r], acc[jj][r]);
                    acc[jj][r] = fmaf(hv.w, wv[3][r], acc[jj][r]);
                }
            }
        }
        for (; c < CIN; c++) {
            float wv[R];
#pragma unroll
            for (int r = 0; r < R; r++) wv[r] = wp[(size_t)c * COUT + r * 64];
#pragma unroll
            for (int jj = 0; jj < JT; jj++) {
                const float hv = h[jj * CINP + c];
#pragma unroll
                for (int r = 0; r < R; r++)
                    acc[jj][r] = fmaf(hv, wv[r], acc[jj][r]);
            }
        }
#pragma unroll
        for (int jj = 0; jj < JT; jj++)
#pragma unroll
            for (int r = 0; r < R; r++) m[r] = fmaxf(m[r], acc[jj][r]);
        __syncthreads();   // before next pass overwrites h
    }

#pragma unroll
    for (int r = 0; r < R; r++) {
        const int o = obase + r * 64 + lane;
        const float val = fmaxf(bias[o] + m[r], 0.0f);
        if (AMAX) {
            atomicMax((unsigned*)&outf[(size_t)b * COUT + o], __float_as_uint(val));
        } else {
            outf[((size_t)b * S + s) * COUT + o] = val;
        }
    }
}

// ---------------- standalone sa kernel (sa3, COUT split in HALVES) ---------
template<int N, int S, int CF, int COUT, int R, int HALVES, bool AMAX>
__global__ __launch_bounds__(64) void sa_kernel(
    const float* __restrict__ xyz, const float* __restrict__ feat,
    const float* __restrict__ cent, const float* __restrict__ W,
    const float* __restrict__ bias, float* __restrict__ outf, const float r2)
{
    constexpr int CINP = (CF + 3 + 3) & ~3;
    __shared__ int   gi[32];
    __shared__ float h[16 * CINP];
    const int s = blockIdx.x / HALVES;
    const int obase = (blockIdx.x % HALVES) * R * 64;
    sa_body<N, S, CF, COUT, R, AMAX>(xyz, feat, cent, W, bias, outf, r2,
                                     s, blockIdx.y, threadIdx.x, obase, gi, h);
}

// ---------------- fused fps1-quarter || sa1-chunk (512-thr blocks) ---------
template<int S0, int S1, int SOFF, int SCNT>
__global__ __launch_bounds__(512) void fused_fps1_sa_kernel(
    const float* __restrict__ fxyz, float* __restrict__ fnew,
    float* __restrict__ fdd,
    const float* __restrict__ xyz, const float* __restrict__ feat,
    const float* __restrict__ cent, const float* __restrict__ W,
    const float* __restrict__ bias, float* __restrict__ outf, const float r2)
{
    constexpr int CINP = 8;   // CF=3 -> CIN=6 -> pad 8
    if (blockIdx.x < B_SZ) {
        __builtin_amdgcn_s_setprio(3);   // protect the serial chain
        fps_body<4096, 512, 512, S0, S1, false>(fxyz, fnew, fdd, blockIdx.x);
    } else {
        __shared__ int   gi_s[8][32];
        __shared__ float h_s[8][16 * CINP];
        const int w = threadIdx.x >> 6, lane = threadIdx.x & 63;
        const int widx = (blockIdx.x - B_SZ) * 8 + w;
        const int b = widx / SCNT, s = SOFF + widx % SCNT;
        sa_body<4096, 512, 3, 64, 1, false>(xyz, feat, cent, W, bias, outf, r2,
                                            s, b, lane, 0, gi_s[w], h_s[w]);
    }
}

// ---------------- fused fps_wave || sa kernel (64-thread blocks) -----------
// HALVES: COUT split factor for the sa part. ZERO: fps blocks zero fmx.
template<int NF, int NPF, int N, int S, int CF, int COUT, int R,
         int SOFF, int SCNT, int HALVES, bool ZERO>
__global__ __launch_bounds__(64) void fused_fps_sa_kernel(
    const float* __restrict__ fxyz,  // fps input  (B,NF,3)
    float* __restrict__ fnew,        // fps output (B,NPF,3)
    const float* __restrict__ xyz, const float* __restrict__ feat,
    const float* __restrict__ cent, const float* __restrict__ W,
    const float* __restrict__ bias, float* __restrict__ outf,
    float* __restrict__ fmx, const float r2)
{
    constexpr int CINP = (CF + 3 + 3) & ~3;
    if (blockIdx.x < B_SZ) {
        if (ZERO) {
            ((float4*)fmx)[blockIdx.x * 64 + threadIdx.x] =
                make_float4(0.f, 0.f, 0.f, 0.f);
        }
        __builtin_amdgcn_s_setprio(3);   // protect the serial chain
        fps_wave_body<NF, NPF>(fxyz, fnew, blockIdx.x, threadIdx.x);
    } else {
        __shared__ int   gi[32];
        __shared__ float h[16 * CINP];
        const int i = blockIdx.x - B_SZ;
        const int obase = (i % HALVES) * R * 64;
        const int j = i / HALVES;
        sa_body<N, S, CF, COUT, R, false>(xyz, feat, cent, W, bias, outf, r2,
                                          SOFF + j % SCNT, j / SCNT,
                                          threadIdx.x, obase, gi, h);
    }
}

// ---------------- head part 1: fc1 (parallel, 64 blocks) -------------------
__global__ __launch_bounds__(64) void fc1_kernel(
    const float* __restrict__ f,     // (16,256) pooled features
    const float* __restrict__ w,     // (256,256)
    const float* __restrict__ bias,  // (256)
    float* __restrict__ x1h)         // (16,256) pre-BN fc1 output
{
    const int r = blockIdx.x >> 2;
    const int o = (blockIdx.x & 3) * 64 + threadIdx.x;
    const float* fr = f + r * 256;   // wave-uniform reads (scalar loads)
    float acc = bias[o];
    for (int c = 0; c < 256; c += 4) {
        acc = fmaf(fr[c + 0], w[(size_t)(c + 0) * 256 + o], acc);
        acc = fmaf(fr[c + 1], w[(size_t)(c + 1) * 256 + o], acc);
        acc = fmaf(fr[c + 2], w[(size_t)(c + 2) * 256 + o], acc);
        acc = fmaf(fr[c + 3], w[(size_t)(c + 3) * 256 + o], acc);
    }
    x1h[r * 256 + o] = acc;
}

// ---------------- head part 2: bn1+relu, fc2+bn2+relu, fc3 -----------------
__global__ __launch_bounds__(256) void head2_kernel(
    const float* __restrict__ x1h,   // (16,256) fc1 output
    const float* __restrict__ fc2_w, const float* __restrict__ fc2_b,
    const float* __restrict__ fc3_w, const float* __restrict__ fc3_b,
    const float* __restrict__ bn1_g, const float* __restrict__ bn1_b,
    const float* __restrict__ bn2_g, const float* __restrict__ bn2_b,
    float* __restrict__ out)         // (16,12)
{
    __shared__ float x1[16 * 257];
    __shared__ float x2[16 * 129];
    const int tid = threadIdx.x;

    for (int idx = tid; idx < 16 * 256; idx += 256) {
        const int r = idx >> 8, c = idx & 255;
        x1[r * 257 + c] = x1h[idx];
    }
    __syncthreads();
    // bn1 + relu (per output channel, batch of 16)
    {
        const int o = tid;
        float v[16];
#pragma unroll
        for (int r = 0; r < 16; r++) v[r] = x1[r * 257 + o];
        float m = 0.0f;
#pragma unroll
        for (int r = 0; r < 16; r++) m += v[r];
        m *= (1.0f / 16.0f);
        float var = 0.0f;
#pragma unroll
        for (int r = 0; r < 16; r++) { const float d = v[r] - m; var += d * d; }
        var *= (1.0f / 16.0f);
        const float sc = bn1_g[o] / sqrtf(var + 1e-5f);
        const float sh = bn1_b[o];
#pragma unroll
        for (int r = 0; r < 16; r++)
            x1[r * 257 + o] = fmaxf((v[r] - m) * sc + sh, 0.0f);
    }
    __syncthreads();
    // fc2: thread (r,g) -> row r, cols g*8..g*8+7
    {
        const int r = tid >> 4, g = tid & 15;
        float acc[8];
#pragma unroll
        for (int i = 0; i < 8; i++) acc[i] = fc2_b[g * 8 + i];
        const float* wrow = fc2_w + g * 8;
        for (int c = 0; c < 256; c++) {
            const float fv = x1[r * 257 + c];
            const float4* w4 = (const float4*)(wrow + (size_t)c * 128);
#pragma unroll
            for (int q = 0; q < 2; q++) {
                const float4 wv = w4[q];
                acc[q * 4 + 0] = fmaf(fv, wv.x, acc[q * 4 + 0]);
                acc[q * 4 + 1] = fmaf(fv, wv.y, acc[q * 4 + 1]);
                acc[q * 4 + 2] = fmaf(fv, wv.z, acc[q * 4 + 2]);
                acc[q * 4 + 3] = fmaf(fv, wv.w, acc[q * 4 + 3]);
            }
        }
#pragma unroll
        for (int i = 0; i < 8; i++) x2[r * 129 + g * 8 + i] = acc[i];
    }
    __syncthreads();
    // bn2 + relu
    if (tid < 128) {
        const int o = tid;
        float v[16];
#pragma unroll
        for (int r = 0; r < 16; r++) v[r] = x2[r * 129 + o];
        float m = 0.0f;
#pragma unroll
        for (int r = 0; r < 16; r++) m += v[r];
        m *= (1.0f / 16.0f);
        float var = 0.0f;
#pragma unroll
        for (int r = 0; r < 16; r++) { const float d = v[r] - m; var += d * d; }
        var *= (1.0f / 16.0f);
        const float sc = bn2_g[o] / sqrtf(var + 1e-5f);
        const float sh = bn2_b[o];
#pragma unroll
        for (int r = 0; r < 16; r++)
            x2[r * 129 + o] = fmaxf((v[r] - m) * sc + sh, 0.0f);
    }
    __syncthreads();
    // fc3: 16x12 outputs
    if (tid < 192) {
        const int r = tid / 12, j = tid - r * 12;
        float acc = fc3_b[j];
        for (int c = 0; c < 128; c++)
            acc = fmaf(x2[r * 129 + c], fc3_w[c * 12 + j], acc);
        out[r * 12 + j] = acc;
    }
}

// ---------------------------------------------------------------------------
extern "C" void kernel_launch(void* const* d_in, const int* in_sizes, int n_in,
                              void* d_out, int out_size, void* d_ws, size_t ws_size,
                              hipStream_t stream) {
    const float* points = (const float*)d_in[0];
    const float* W1     = (const float*)d_in[1];
    const float* b1     = (const float*)d_in[2];
    const float* W2     = (const float*)d_in[3];
    const float* b2     = (const float*)d_in[4];
    const float* W3     = (const float*)d_in[5];
    const float* b3     = (const float*)d_in[6];
    const float* fc1_w  = (const float*)d_in[7];
    const float* fc1_b  = (const float*)d_in[8];
    const float* fc2_w  = (const float*)d_in[9];
    const float* fc2_b  = (const float*)d_in[10];
    const float* fc3_w  = (const float*)d_in[11];
    const float* fc3_b  = (const float*)d_in[12];
    const float* bn1_g  = (const float*)d_in[13];
    const float* bn1_b  = (const float*)d_in[14];
    const float* bn2_g  = (const float*)d_in[15];
    const float* bn2_b  = (const float*)d_in[16];
    float* out = (float*)d_out;

    float* ws   = (float*)d_ws;
    float* nx1  = ws;                 // 16*512*3   = 24576
    float* f1   = nx1 + 24576;        // 16*512*64  = 524288
    float* nx2  = f1  + 524288;       // 16*256*3   = 12288
    float* f2   = nx2 + 12288;        // 16*256*128 = 524288
    float* nx3  = f2  + 524288;       // 16*128*3   = 6144
    float* fmx  = nx3 + 6144;         // 16*256     = 4096
    float* fdd  = fmx + 4096;         // 16*4096    = 65536 (fps1 dd carry)
    float* x1h  = fdd + 65536;        // 16*256     = 4096  (fc1 output)

    const float r21 = (float)(0.2 * 0.2);
    // fps1 q1 (centers 0..127; nothing to overlap - no sa work ready)
    fps_kernel<4096, 512, 512, 1, 128, true><<<B_SZ, 512, 0, stream>>>(
        points, nx1, fdd);
    // fps1 q2 || sa1(0..127)
    fused_fps1_sa_kernel<128, 256, 0, 128><<<B_SZ + 256, 512, 0, stream>>>(
        points, nx1, fdd, points, points, nx1, W1, b1, f1, r21);
    // fps1 q3 || sa1(128..255)
    fused_fps1_sa_kernel<256, 384, 128, 128><<<B_SZ + 256, 512, 0, stream>>>(
        points, nx1, fdd, points, points, nx1, W1, b1, f1, r21);
    // fps1 q4 || sa1(256..383)
    fused_fps1_sa_kernel<384, 512, 256, 128><<<B_SZ + 256, 512, 0, stream>>>(
        points, nx1, fdd, points, points, nx1, W1, b1, f1, r21);
    // fps2 || sa1(384..511); fps blocks also zero fmx for sa3's atomicMax
    fused_fps_sa_kernel<512, 256, 4096, 512, 3, 64, 1, 384, 128, 1, true>
        <<<B_SZ + 128 * B_SZ, 64, 0, stream>>>(
        nx1, nx2, points, points, nx1, W1, b1, f1, fmx, r21);
    // fps3 || sa2 (whole, unsplit - R16's split cost more than it saved)
    fused_fps_sa_kernel<256, 128, 512, 256, 64, 128, 2, 0, 256, 1, false>
        <<<B_SZ + 256 * B_SZ, 64, 0, stream>>>(
        nx2, nx3, nx1, f1, nx2, W2, b2, f2, fmx, (float)(0.4 * 0.4));
    // sa3 with fused global maxpool, COUT split in 2 (proven: 110 -> <92us)
    sa_kernel<256, 128, 128, 256, 2, 2, true>
        <<<dim3(128 * 2, B_SZ), 64, 0, stream>>>(
        nx2, f2, nx3, W3, b3, fmx, (float)(0.8 * 0.8));
    // head: parallel fc1, then bn/fc2/bn/fc3
    fc1_kernel<<<64, 64, 0, stream>>>(fmx, fc1_w, fc1_b, x1h);
    head2_kernel<<<1, 256, 0, stream>>>(x1h, fc2_w, fc2_b, fc3_w, fc3_b,
                                        bn1_g, bn1_b, bn2_g, bn2_b, out);
}